// Round 2
// baseline (3026.836 us; speedup 1.0000x reference)
//
#include <hip/hip_runtime.h>
#include <hip/hip_bf16.h>

#define DIM 256
#define NHEADS 4
#define HDIM 64
#define NPIX 2304          // 48*48
#define NBATCH 8
#define SCALE 0.125f       // 64^-0.5
#define CLAMPV 6.0f

typedef __hip_bfloat16 bf16;

__device__ __forceinline__ float tof(const bf16 x) { return __bfloat162float(x); }
__device__ __forceinline__ float tof(const float x) { return x; }

// Y = W(256x256) * X(256xNPIX) + bias, per batch. Inputs f32.
// TRANS: store bf16 transposed as (b, h, n, d) into Yt (for Q/K/V).
// else : store f32 as (b, c, n) into Yf (final output).
template <typename XT, bool TRANS>
__global__ __launch_bounds__(256) void conv1x1_kernel(
    const float* __restrict__ Wm, const float* __restrict__ bias,
    const XT* __restrict__ X, bf16* __restrict__ Yt, float* __restrict__ Yf)
{
    const int b  = blockIdx.z;
    const int m0 = blockIdx.y * 64;
    const int n0 = blockIdx.x * 64;
    const int tx = threadIdx.x, ty = threadIdx.y;
    const int t  = ty * 16 + tx;

    __shared__ float Ws[64][17];
    __shared__ float Xs[16][65];

    float acc[4][4];
#pragma unroll
    for (int i = 0; i < 4; ++i)
#pragma unroll
        for (int j = 0; j < 4; ++j) acc[i][j] = 0.f;

    for (int kt = 0; kt < 16; ++kt) {
#pragma unroll
        for (int i = 0; i < 4; ++i) {
            int lin = t + i * 256;
            {   // W tile: 64 rows x 16 k
                int r = lin >> 4, c = lin & 15;
                Ws[r][c] = Wm[(size_t)(m0 + r) * DIM + kt * 16 + c];
            }
            {   // X tile: 16 k x 64 cols
                int r = lin >> 6, c = lin & 63;
                Xs[r][c] = tof(X[((size_t)b * DIM + kt * 16 + r) * NPIX + n0 + c]);
            }
        }
        __syncthreads();
#pragma unroll
        for (int k = 0; k < 16; ++k) {
            float a[4], x[4];
#pragma unroll
            for (int i = 0; i < 4; ++i) a[i] = Ws[ty * 4 + i][k];
#pragma unroll
            for (int j = 0; j < 4; ++j) x[j] = Xs[k][tx * 4 + j];
#pragma unroll
            for (int i = 0; i < 4; ++i)
#pragma unroll
                for (int j = 0; j < 4; ++j) acc[i][j] += a[i] * x[j];
        }
        __syncthreads();
    }

    float bv[4];
#pragma unroll
    for (int i = 0; i < 4; ++i) bv[i] = bias[m0 + ty * 4 + i];

#pragma unroll
    for (int i = 0; i < 4; ++i) {
        int m = m0 + ty * 4 + i;
#pragma unroll
        for (int j = 0; j < 4; ++j) {
            int n = n0 + tx * 4 + j;
            float v = acc[i][j] + bv[i];
            if (TRANS) {
                int h = m >> 6, d = m & 63;
                Yt[(((size_t)b * NHEADS + h) * NPIX + n) * HDIM + d] = __float2bfloat16(v);
            } else {
                Yf[((size_t)b * DIM + m) * NPIX + n] = v;
            }
        }
    }
}

// Flash-style attention. Q/K/V in ws as bf16 (b,h,n,d). Output Op bf16 (b,c,n).
// Block: one (b, h, 32-query tile); 256 threads = 32 queries x 8 subs.
__global__ __launch_bounds__(256) void attn_kernel(
    const bf16* __restrict__ Qt, const bf16* __restrict__ Kt,
    const bf16* __restrict__ Vt, bf16* __restrict__ Op)
{
    const int b  = blockIdx.z, h = blockIdx.y;
    const int n0 = blockIdx.x * 32;
    const int t  = threadIdx.x;
    const int q  = t >> 3, sub = t & 7;

    __shared__ float q_s[32][68];   // stride 68: float4-aligned, bank-spread
    __shared__ float k_s[64][68];
    __shared__ float v_s[64][68];
    __shared__ float p_s[32][68];

    const size_t base = ((size_t)b * NHEADS + h) * (size_t)NPIX * HDIM;
    const bf16* Qb = Qt + base;
    const bf16* Kb = Kt + base;
    const bf16* Vb = Vt + base;

#pragma unroll
    for (int i = 0; i < 8; ++i) {
        int lin = t + i * 256; int r = lin >> 6, c = lin & 63;
        q_s[r][c] = tof(Qb[(size_t)(n0 + r) * HDIM + c]);
    }

    float mrun = -1e30f, lrun = 0.f;
    float o[8];
#pragma unroll
    for (int j = 0; j < 8; ++j) o[j] = 0.f;
    __syncthreads();

    for (int kt = 0; kt < NPIX / 64; ++kt) {
#pragma unroll
        for (int i = 0; i < 16; ++i) {
            int lin = t + i * 256; int r = lin >> 6, c = lin & 63;
            k_s[r][c] = tof(Kb[(size_t)(kt * 64 + r) * HDIM + c]);
            v_s[r][c] = tof(Vb[(size_t)(kt * 64 + r) * HDIM + c]);
        }
        __syncthreads();

        // scores: thread (q,sub) handles keys {sub, 8+sub, ..., 56+sub}
        float acc[8];
#pragma unroll
        for (int j = 0; j < 8; ++j) acc[j] = 0.f;
        for (int d = 0; d < 64; d += 4) {
            float4 q4 = *(const float4*)&q_s[q][d];
#pragma unroll
            for (int j = 0; j < 8; ++j) {
                float4 k4 = *(const float4*)&k_s[j * 8 + sub][d];
                acc[j] += q4.x * k4.x + q4.y * k4.y + q4.z * k4.z + q4.w * k4.w;
            }
        }
        float tmax = -1e30f;
#pragma unroll
        for (int j = 0; j < 8; ++j) {
            float s = fminf(fmaxf(acc[j] * SCALE, -CLAMPV), CLAMPV);
            acc[j] = s; tmax = fmaxf(tmax, s);
        }
#pragma unroll
        for (int off = 1; off < 8; off <<= 1) tmax = fmaxf(tmax, __shfl_xor(tmax, off, 8));

        float newm  = fmaxf(mrun, tmax);
        float fact  = __expf(mrun - newm);
        float psum  = 0.f;
#pragma unroll
        for (int j = 0; j < 8; ++j) {
            float e = __expf(acc[j] - newm);
            psum += e;
            p_s[q][j * 8 + sub] = e;
        }
#pragma unroll
        for (int off = 1; off < 8; off <<= 1) psum += __shfl_xor(psum, off, 8);
        lrun = lrun * fact + psum;
        mrun = newm;
#pragma unroll
        for (int j = 0; j < 8; ++j) o[j] *= fact;
        __syncthreads();

        // PV: thread (q,sub) owns d = sub*8 .. sub*8+7
        for (int mm = 0; mm < 64; ++mm) {
            float p   = p_s[q][mm];
            float4 va = *(const float4*)&v_s[mm][sub * 8];
            float4 vb = *(const float4*)&v_s[mm][sub * 8 + 4];
            o[0] += p * va.x; o[1] += p * va.y; o[2] += p * va.z; o[3] += p * va.w;
            o[4] += p * vb.x; o[5] += p * vb.y; o[6] += p * vb.z; o[7] += p * vb.w;
        }
        __syncthreads();
    }

    float inv = 1.f / lrun;
    int n = n0 + q;
#pragma unroll
    for (int j = 0; j < 8; ++j) {
        int d = sub * 8 + j;
        Op[((size_t)b * DIM + h * HDIM + d) * NPIX + n] = __float2bfloat16(o[j] * inv);
    }
}

extern "C" void kernel_launch(void* const* d_in, const int* in_sizes, int n_in,
                              void* d_out, int out_size, void* d_ws, size_t ws_size,
                              hipStream_t stream) {
    const float* src = (const float*)d_in[0];
    const float* tgt = (const float*)d_in[1];
    const float* qw  = (const float*)d_in[2];
    const float* qb  = (const float*)d_in[3];
    const float* kw  = (const float*)d_in[4];
    const float* kb  = (const float*)d_in[5];
    const float* vw  = (const float*)d_in[6];
    const float* vb  = (const float*)d_in[7];
    const float* ow  = (const float*)d_in[8];
    const float* ob  = (const float*)d_in[9];
    float* out = (float*)d_out;

    const size_t TEN = (size_t)NBATCH * DIM * NPIX;  // 4,718,592 elems
    bf16* Qt = (bf16*)d_ws;
    bf16* Kt = Qt + TEN;
    bf16* Vt = Kt + TEN;
    bf16* Op = Vt + TEN;   // bf16 (b,c,n)

    dim3 cgrid(NPIX / 64, DIM / 64, NBATCH);
    dim3 cblk(16, 16);
    conv1x1_kernel<float, true><<<cgrid, cblk, 0, stream>>>(qw, qb, src, Qt, nullptr);
    conv1x1_kernel<float, true><<<cgrid, cblk, 0, stream>>>(kw, kb, tgt, Kt, nullptr);
    conv1x1_kernel<float, true><<<cgrid, cblk, 0, stream>>>(vw, vb, tgt, Vt, nullptr);

    attn_kernel<<<dim3(NPIX / 32, NHEADS, NBATCH), 256, 0, stream>>>(Qt, Kt, Vt, Op);

    conv1x1_kernel<bf16, false><<<cgrid, cblk, 0, stream>>>(ow, ob, Op, nullptr, out);
}

// Round 3
// 543.741 us; speedup vs baseline: 5.5667x; 5.5667x over previous
//
#include <hip/hip_runtime.h>
#include <hip/hip_bf16.h>

#define DIM 256
#define NHEADS 4
#define HDIM 64
#define NPIX 2304          // 48*48
#define NBATCH 8
#define SCALE_L2E 0.18033688011112042f   // 0.125 * log2(e)
#define CLAMP_L2E 8.656170245332781f     // 6.0  * log2(e)

typedef __hip_bfloat16 bf16;
typedef __bf16 bf16x8 __attribute__((ext_vector_type(8)));
typedef float  f32x4  __attribute__((ext_vector_type(4)));

__device__ __forceinline__ float tof(const bf16 x) { return __bfloat162float(x); }
__device__ __forceinline__ float tof(const float x) { return x; }

__device__ __forceinline__ unsigned short f2bf_bits(float x) {
    union { float f; unsigned int u; } c; c.f = x;
    unsigned int r = (c.u + 0x7FFFu + ((c.u >> 16) & 1u)) >> 16;  // RNE, finite inputs
    return (unsigned short)r;
}
__device__ __forceinline__ float bf2f(unsigned short b) {
    union { unsigned int u; float f; } c; c.u = ((unsigned int)b) << 16;
    return c.f;
}

// Y = W(256x256) * X(256xNPIX) + bias, per batch. W,bias f32.
// MODE 0: f32 natural (b,c,n) -> Yf     (final output)
// MODE 1: bf16 transposed (b,h,n,d) -> Yt   (Q, K)
// MODE 2: bf16 natural (b,c,n) -> Yt        (V, attn output staging)
template <typename XT, int MODE>
__global__ __launch_bounds__(256) void conv1x1_kernel(
    const float* __restrict__ Wm, const float* __restrict__ bias,
    const XT* __restrict__ X, bf16* __restrict__ Yt, float* __restrict__ Yf)
{
    const int b  = blockIdx.z;
    const int m0 = blockIdx.y * 64;
    const int n0 = blockIdx.x * 64;
    const int tx = threadIdx.x, ty = threadIdx.y;
    const int t  = ty * 16 + tx;

    __shared__ float Ws[64][17];
    __shared__ float Xs[16][65];

    float acc[4][4];
#pragma unroll
    for (int i = 0; i < 4; ++i)
#pragma unroll
        for (int j = 0; j < 4; ++j) acc[i][j] = 0.f;

    for (int kt = 0; kt < 16; ++kt) {
#pragma unroll
        for (int i = 0; i < 4; ++i) {
            int lin = t + i * 256;
            {   // W tile: 64 rows x 16 k
                int r = lin >> 4, c = lin & 15;
                Ws[r][c] = Wm[(size_t)(m0 + r) * DIM + kt * 16 + c];
            }
            {   // X tile: 16 k x 64 cols
                int r = lin >> 6, c = lin & 63;
                Xs[r][c] = tof(X[((size_t)b * DIM + kt * 16 + r) * NPIX + n0 + c]);
            }
        }
        __syncthreads();
#pragma unroll
        for (int k = 0; k < 16; ++k) {
            float a[4], x[4];
#pragma unroll
            for (int i = 0; i < 4; ++i) a[i] = Ws[ty * 4 + i][k];
#pragma unroll
            for (int j = 0; j < 4; ++j) x[j] = Xs[k][tx * 4 + j];
#pragma unroll
            for (int i = 0; i < 4; ++i)
#pragma unroll
                for (int j = 0; j < 4; ++j) acc[i][j] += a[i] * x[j];
        }
        __syncthreads();
    }

    float bv[4];
#pragma unroll
    for (int i = 0; i < 4; ++i) bv[i] = bias[m0 + ty * 4 + i];

#pragma unroll
    for (int i = 0; i < 4; ++i) {
        int m = m0 + ty * 4 + i;
#pragma unroll
        for (int j = 0; j < 4; ++j) {
            int n = n0 + tx * 4 + j;
            float v = acc[i][j] + bv[i];
            if (MODE == 1) {
                int h = m >> 6, d = m & 63;
                Yt[(((size_t)b * NHEADS + h) * NPIX + n) * HDIM + d] = __float2bfloat16(v);
            } else if (MODE == 2) {
                Yt[((size_t)b * DIM + m) * NPIX + n] = __float2bfloat16(v);
            } else {
                Yf[((size_t)b * DIM + m) * NPIX + n] = v;
            }
        }
    }
}

// MFMA flash attention (no online max needed: logits clamped to +-6).
// Q,K in (b,h,n,d) bf16; V in natural (b,c,n) bf16; out Op natural (b,c,n) bf16.
// Block: (b, h, 64 queries) = 4 waves x 16 queries. Loop keys in chunks of 32.
__global__ __launch_bounds__(256) void attn_kernel(
    const bf16* __restrict__ Qt, const bf16* __restrict__ Kt,
    const bf16* __restrict__ Vt, bf16* __restrict__ Op)
{
    const int b  = blockIdx.z, h = blockIdx.y;
    const int w  = threadIdx.x >> 6;     // wave 0..3
    const int l  = threadIdx.x & 63;     // lane
    const int lo = l & 15;               // col index in fragments
    const int hi = l >> 4;               // 16-lane group 0..3
    const int n0 = blockIdx.x * 64 + w * 16;   // this wave's first query

    // per-wave ping-pong P tile: 16 rows x 32 cols, row stride 40 shorts (80B,
    // 16B-aligned; b128 reads land <=2-way bank aliasing = free)
    __shared__ unsigned short P_lds[4][2][16][40];

    const size_t qkbase = ((size_t)b * NHEADS + h) * (size_t)NPIX * HDIM;
    const bf16* Qb = Qt + qkbase;
    const bf16* Kb = Kt + qkbase;
    const bf16* Vb = Vt + ((size_t)b * DIM + h * HDIM) * (size_t)NPIX;

    // Q fragments, kept in registers: lane holds Q[n0+lo][kk*32 + hi*8 .. +8]
    bf16x8 qf[2];
#pragma unroll
    for (int kk = 0; kk < 2; ++kk)
        qf[kk] = *(const bf16x8*)(const void*)(Qb + (size_t)(n0 + lo) * HDIM + kk * 32 + hi * 8);

    f32x4 oacc[4];
#pragma unroll
    for (int dt = 0; dt < 4; ++dt) oacc[dt] = (f32x4){0.f, 0.f, 0.f, 0.f};
    float lsum = 0.f;

    int pp = 0;
    for (int k0 = 0; k0 < NPIX; k0 += 32) {
        // ---- S = Q K^T for 16q x 32 keys (two 16-key tiles, 2 k-steps each)
        f32x4 s[2];
#pragma unroll
        for (int j = 0; j < 2; ++j) {
            f32x4 acc = (f32x4){0.f, 0.f, 0.f, 0.f};
#pragma unroll
            for (int kk = 0; kk < 2; ++kk) {
                bf16x8 kf = *(const bf16x8*)(const void*)(
                    Kb + (size_t)(k0 + j * 16 + lo) * HDIM + kk * 32 + hi * 8);
                acc = __builtin_amdgcn_mfma_f32_16x16x32_bf16(qf[kk], kf, acc, 0, 0, 0);
            }
            s[j] = acc;
        }
        // ---- P = exp2(clamp(S*scale*log2e)); stash to LDS (D-layout -> A-layout)
#pragma unroll
        for (int j = 0; j < 2; ++j) {
#pragma unroll
            for (int r = 0; r < 4; ++r) {
                float sv = s[j][r] * SCALE_L2E;
                sv = fminf(fmaxf(sv, -CLAMP_L2E), CLAMP_L2E);
                float e = exp2f(sv);
                P_lds[w][pp][hi * 4 + r][j * 16 + lo] = f2bf_bits(e);
            }
        }
        // ---- read back as PV A-fragment (16B/lane) + row-sum accumulation
        union { bf16x8 v; unsigned short u[8]; } pf;
        pf.v = *(const bf16x8*)&P_lds[w][pp][lo][hi * 8];
#pragma unroll
        for (int j2 = 0; j2 < 8; ++j2) lsum += bf2f(pf.u[j2]);
        // ---- O += P V (4 d-tiles of 16)
#pragma unroll
        for (int dt = 0; dt < 4; ++dt) {
            bf16x8 vf = *(const bf16x8*)(const void*)(
                Vb + (size_t)(dt * 16 + lo) * NPIX + k0 + hi * 8);
            oacc[dt] = __builtin_amdgcn_mfma_f32_16x16x32_bf16(pf.v, vf, oacc[dt], 0, 0, 0);
        }
        pp ^= 1;
    }

    // full row sums: merge the 4 lane-groups (each covered a different m-slice)
    lsum += __shfl_xor(lsum, 16);
    lsum += __shfl_xor(lsum, 32);
    // rowsum for query row q (0..15) now lives in lane q (among others)
    float inv[4];
#pragma unroll
    for (int r = 0; r < 4; ++r) inv[r] = 1.f / __shfl(lsum, hi * 4 + r);

    // store: O[q][d] -> Op[(b, h*64+d, n0+q)]; pack pairs along n (4B stores)
    const size_t cbase = (size_t)b * DIM + h * HDIM;
    const int nbase = n0 + hi * 4;   // 4 consecutive n per lane (even)
#pragma unroll
    for (int dt = 0; dt < 4; ++dt) {
        float v0 = oacc[dt][0] * inv[0];
        float v1 = oacc[dt][1] * inv[1];
        float v2 = oacc[dt][2] * inv[2];
        float v3 = oacc[dt][3] * inv[3];
        unsigned int u01 = (unsigned int)f2bf_bits(v0) | ((unsigned int)f2bf_bits(v1) << 16);
        unsigned int u23 = (unsigned int)f2bf_bits(v2) | ((unsigned int)f2bf_bits(v3) << 16);
        bf16* p = (bf16*)Op + (cbase + dt * 16 + lo) * NPIX + nbase;
        *(unsigned int*)(void*)(p)     = u01;
        *(unsigned int*)(void*)(p + 2) = u23;
    }
}

extern "C" void kernel_launch(void* const* d_in, const int* in_sizes, int n_in,
                              void* d_out, int out_size, void* d_ws, size_t ws_size,
                              hipStream_t stream) {
    const float* src = (const float*)d_in[0];
    const float* tgt = (const float*)d_in[1];
    const float* qw  = (const float*)d_in[2];
    const float* qb  = (const float*)d_in[3];
    const float* kw  = (const float*)d_in[4];
    const float* kb  = (const float*)d_in[5];
    const float* vw  = (const float*)d_in[6];
    const float* vb  = (const float*)d_in[7];
    const float* ow  = (const float*)d_in[8];
    const float* ob  = (const float*)d_in[9];
    float* out = (float*)d_out;

    const size_t TEN = (size_t)NBATCH * DIM * NPIX;  // 4,718,592 elems
    bf16* Qt = (bf16*)d_ws;          // (b,h,n,d)
    bf16* Kt = Qt + TEN;             // (b,h,n,d)
    bf16* Vt = Kt + TEN;             // (b,c,n) natural
    bf16* Op = Vt + TEN;             // (b,c,n) natural

    dim3 cgrid(NPIX / 64, DIM / 64, NBATCH);
    dim3 cblk(16, 16);
    conv1x1_kernel<float, 1><<<cgrid, cblk, 0, stream>>>(qw, qb, src, Qt, nullptr);
    conv1x1_kernel<float, 1><<<cgrid, cblk, 0, stream>>>(kw, kb, tgt, Kt, nullptr);
    conv1x1_kernel<float, 2><<<cgrid, cblk, 0, stream>>>(vw, vb, tgt, Vt, nullptr);

    attn_kernel<<<dim3(NPIX / 64, NHEADS, NBATCH), 256, 0, stream>>>(Qt, Kt, Vt, Op);

    conv1x1_kernel<bf16, 0><<<cgrid, cblk, 0, stream>>>(ow, ob, Op, nullptr, out);
}

// Round 6
// 509.121 us; speedup vs baseline: 5.9452x; 1.0680x over previous
//
#include <hip/hip_runtime.h>
#include <hip/hip_bf16.h>

#define DIM 256
#define NHEADS 4
#define HDIM 64
#define NPIX 2304          // 48*48
#define NBATCH 8
#define SCALE_L2E 0.18033688011112042f   // 0.125 * log2(e), folded into Q
#define CLAMP_L2E 8.656170245332781f     // 6.0  * log2(e)

typedef __hip_bfloat16 bf16;
typedef __bf16 bf16x8 __attribute__((ext_vector_type(8)));
typedef float  f32x4  __attribute__((ext_vector_type(4)));

__device__ __forceinline__ unsigned int pack2bf(float a, float b) {
    __hip_bfloat162 h = __float22bfloat162_rn(float2{a, b});
    union { __hip_bfloat162 h; unsigned int u; } c; c.h = h;
    return c.u;
}

// ---- 4 weight matrices (256x256 f32, row-major (m,c)) -> bf16, concatenated.
__global__ __launch_bounds__(256) void cvt_w_kernel(
    const float* __restrict__ w0, const float* __restrict__ w1,
    const float* __restrict__ w2, const float* __restrict__ w3,
    bf16* __restrict__ out)
{
    const int sel = blockIdx.y;
    const float* src = sel == 0 ? w0 : sel == 1 ? w1 : sel == 2 ? w2 : w3;
    const int i = (blockIdx.x * 256 + threadIdx.x) * 8;
    float4 a = *(const float4*)(src + i);
    float4 b = *(const float4*)(src + i + 4);
    uint4 u;
    u.x = pack2bf(a.x, a.y); u.y = pack2bf(a.z, a.w);
    u.z = pack2bf(b.x, b.y); u.w = pack2bf(b.z, b.w);
    *(uint4*)(void*)(out + (size_t)sel * 65536 + i) = u;
}

// ---- src/tgt (b,c,n) f32 -> (b,n,c) bf16 via LDS tile transpose.
__global__ __launch_bounds__(256) void txp_kernel(
    const float* __restrict__ src, const float* __restrict__ tgt,
    bf16* __restrict__ oS, bf16* __restrict__ oT)
{
    const int b = blockIdx.z & 7;
    const float* in = (blockIdx.z >> 3) ? tgt : src;
    bf16* out = (blockIdx.z >> 3) ? oT : oS;
    const int n0 = blockIdx.x * 64, c0 = blockIdx.y * 64;
    __shared__ float tile[64][65];
    const int t = threadIdx.x;
#pragma unroll
    for (int i = 0; i < 4; ++i) {
        int idx = t + i * 256;
        int cl = idx >> 4, n4 = (idx & 15) * 4;
        float4 v = *(const float4*)(in + ((size_t)b * DIM + c0 + cl) * NPIX + n0 + n4);
        tile[cl][n4] = v.x; tile[cl][n4 + 1] = v.y;
        tile[cl][n4 + 2] = v.z; tile[cl][n4 + 3] = v.w;
    }
    __syncthreads();
#pragma unroll
    for (int i = 0; i < 2; ++i) {
        int idx = t + i * 256;
        int nl = idx >> 3, c8 = (idx & 7) * 8;
        uint4 u;
        u.x = pack2bf(tile[c8 + 0][nl], tile[c8 + 1][nl]);
        u.y = pack2bf(tile[c8 + 2][nl], tile[c8 + 3][nl]);
        u.z = pack2bf(tile[c8 + 4][nl], tile[c8 + 5][nl]);
        u.w = pack2bf(tile[c8 + 6][nl], tile[c8 + 7][nl]);
        *(uint4*)(void*)(out + ((size_t)b * NPIX + n0 + nl) * DIM + c0 + c8) = u;
    }
}

// ---- 1x1 conv as MFMA GEMM: D[n][m] = sum_c X[n][c] * W[m][c] + bias[m].
// X: (b,n,c) bf16; W: (m,c) bf16. Block: 64 n x 128 m, 4 waves (16 n each).
// MODE 0: f32 natural (b,c,n) -> Yf (final out). MODE 1: bf16 (b,h,n,d)*scale -> Yb (Q,K).
// MODE 2: bf16 (b,c,n) -> Yb (V).
template <int MODE>
__global__ __launch_bounds__(256) void conv_kernel(
    const bf16* __restrict__ X, const bf16* __restrict__ Wb,
    const float* __restrict__ bias, float scale,
    bf16* __restrict__ Yb, float* __restrict__ Yf)
{
    const int b  = blockIdx.z, mh = blockIdx.y;
    const int n0 = blockIdx.x * 64;
    const int w  = threadIdx.x >> 6, l = threadIdx.x & 63;
    const int lo = l & 15, hi = l >> 4;
    const int nrow = n0 + w * 16 + lo;

    const bf16* xp = X + ((size_t)b * NPIX + nrow) * DIM + hi * 8;
    const bf16* wp = Wb + ((size_t)(mh * 128 + lo)) * DIM + hi * 8;

    f32x4 acc[8];
#pragma unroll
    for (int mt = 0; mt < 8; ++mt) acc[mt] = (f32x4){0.f, 0.f, 0.f, 0.f};

#pragma unroll 2
    for (int k0 = 0; k0 < DIM; k0 += 32) {
        bf16x8 a = *(const bf16x8*)(const void*)(xp + k0);
#pragma unroll
        for (int mt = 0; mt < 8; ++mt) {
            bf16x8 bf = *(const bf16x8*)(const void*)(wp + (size_t)mt * 16 * DIM + k0);
            acc[mt] = __builtin_amdgcn_mfma_f32_16x16x32_bf16(a, bf, acc[mt], 0, 0, 0);
        }
    }

    const int nb = n0 + w * 16 + hi * 4;   // first of 4 consecutive n (rows r)
#pragma unroll
    for (int mt = 0; mt < 8; ++mt) {
        const int m = mh * 128 + mt * 16 + lo;
        const float bv = bias[m];
        if (MODE == 1) {
            const int h = m >> 6, d = m & 63;
            bf16* p = Yb + (((size_t)b * NHEADS + h) * NPIX + nb) * HDIM + d;
#pragma unroll
            for (int r = 0; r < 4; ++r)
                p[(size_t)r * HDIM] = __float2bfloat16((acc[mt][r] + bv) * scale);
        } else if (MODE == 2) {
            bf16* p = Yb + ((size_t)b * DIM + m) * NPIX + nb;
            *(unsigned int*)(void*)(p)     = pack2bf(acc[mt][0] + bv, acc[mt][1] + bv);
            *(unsigned int*)(void*)(p + 2) = pack2bf(acc[mt][2] + bv, acc[mt][3] + bv);
        } else {
            float4 v = make_float4(acc[mt][0] + bv, acc[mt][1] + bv,
                                   acc[mt][2] + bv, acc[mt][3] + bv);
            *(float4*)(void*)(Yf + ((size_t)b * DIM + m) * NPIX + nb) = v;
        }
    }
}

// ---- MFMA flash attention, no LDS. Q prescaled by SCALE_L2E.
// Q,K: (b,h,n,d) bf16. V: (b,c,n) bf16. Out Op: (b,n,c) bf16.
// Block: (b,h,64 q) = 4 waves x 16 q. Keys in chunks of 32.
// QK^T computed swapped (A=K, B=Q) so lane owns query column lo; the
// D->A layout fix for PV is cvt_pk + 8 shfl + 4 selects (no LDS roundtrip).
__global__ __launch_bounds__(256) void attn_kernel(
    const bf16* __restrict__ Qt, const bf16* __restrict__ Kt,
    const bf16* __restrict__ Vt, bf16* __restrict__ Op)
{
    const int b = blockIdx.z, h = blockIdx.y;
    const int w = threadIdx.x >> 6, l = threadIdx.x & 63;
    const int lo = l & 15, hi = l >> 4;
    const int nq = blockIdx.x * 64 + w * 16;

    const size_t qkb = ((size_t)b * NHEADS + h) * (size_t)NPIX * HDIM;
    const bf16* Qb = Qt + qkb;
    const bf16* Kb = Kt + qkb;
    const bf16* Vb = Vt + ((size_t)b * DIM + h * HDIM) * (size_t)NPIX;

    bf16x8 qf[2];
#pragma unroll
    for (int kk = 0; kk < 2; ++kk)
        qf[kk] = *(const bf16x8*)(const void*)(Qb + (size_t)(nq + lo) * HDIM + kk * 32 + hi * 8);

    const int srcA = ((hi & 1) << 5) + lo;   // source lane hi' = 2*(hi&1)
    const int srcB = srcA + 16;              // source lane hi' = 2*(hi&1)+1
    const bool jtHi = hi >= 2;               // target needs keys from jt' = hi>>1

    const bf16* kpb = Kb + (size_t)lo * HDIM + hi * 8;

    f32x4 oacc[4];
#pragma unroll
    for (int dt = 0; dt < 4; ++dt) oacc[dt] = (f32x4){0.f, 0.f, 0.f, 0.f};
    float lsum = 0.f;

#pragma unroll 2
    for (int k0 = 0; k0 < NPIX; k0 += 32) {
        const bf16* kp = kpb + (size_t)k0 * HDIM;
        f32x4 s0 = (f32x4){0.f, 0.f, 0.f, 0.f};
        f32x4 s1 = (f32x4){0.f, 0.f, 0.f, 0.f};
#pragma unroll
        for (int kk = 0; kk < 2; ++kk) {
            bf16x8 k0f = *(const bf16x8*)(const void*)(kp + kk * 32);
            bf16x8 k1f = *(const bf16x8*)(const void*)(kp + 16 * HDIM + kk * 32);
            s0 = __builtin_amdgcn_mfma_f32_16x16x32_bf16(k0f, qf[kk], s0, 0, 0, 0);
            s1 = __builtin_amdgcn_mfma_f32_16x16x32_bf16(k1f, qf[kk], s1, 0, 0, 0);
        }
        // e = exp2(clamp(S)); lane holds query lo, keys jt*16 + hi*4 + r
        float e0[4], e1[4];
#pragma unroll
        for (int r = 0; r < 4; ++r) {
            e0[r] = exp2f(__builtin_amdgcn_fmed3f(s0[r], -CLAMP_L2E, CLAMP_L2E));
            e1[r] = exp2f(__builtin_amdgcn_fmed3f(s1[r], -CLAMP_L2E, CLAMP_L2E));
            lsum += e0[r] + e1[r];
        }
        unsigned int pkA0 = pack2bf(e0[0], e0[1]), pkB0 = pack2bf(e0[2], e0[3]);
        unsigned int pkA1 = pack2bf(e1[0], e1[1]), pkB1 = pack2bf(e1[2], e1[3]);
        // gather PV A-frag: slots = keys hi*8..hi*8+7 for query lo
        int a0A = __shfl((int)pkA0, srcA), a1A = __shfl((int)pkA1, srcA);
        int b0A = __shfl((int)pkB0, srcA), b1A = __shfl((int)pkB1, srcA);
        int a0B = __shfl((int)pkA0, srcB), a1B = __shfl((int)pkA1, srcB);
        int b0B = __shfl((int)pkB0, srcB), b1B = __shfl((int)pkB1, srcB);
        union { unsigned int u[4]; bf16x8 v; } pf;
        pf.u[0] = (unsigned int)(jtHi ? a1A : a0A);
        pf.u[1] = (unsigned int)(jtHi ? b1A : b0A);
        pf.u[2] = (unsigned int)(jtHi ? a1B : a0B);
        pf.u[3] = (unsigned int)(jtHi ? b1B : b0B);
#pragma unroll
        for (int dt = 0; dt < 4; ++dt) {
            bf16x8 vf = *(const bf16x8*)(const void*)(
                Vb + (size_t)(dt * 16 + lo) * NPIX + k0 + hi * 8);
            oacc[dt] = __builtin_amdgcn_mfma_f32_16x16x32_bf16(pf.v, vf, oacc[dt], 0, 0, 0);
        }
    }

    lsum += __shfl_xor(lsum, 16);
    lsum += __shfl_xor(lsum, 32);
    const float linv = 1.f / lsum;
    float ir[4];
#pragma unroll
    for (int r = 0; r < 4; ++r) ir[r] = __shfl(linv, hi * 4 + r);

    // store Op (b,n,c): n = nq + hi*4 + r, c = h*64 + dt*16 + lo
    bf16* op = Op + ((size_t)b * NPIX + nq + hi * 4) * DIM + h * HDIM + lo;
#pragma unroll
    for (int dt = 0; dt < 4; ++dt)
#pragma unroll
        for (int r = 0; r < 4; ++r)
            op[(size_t)r * DIM + dt * 16] = __float2bfloat16(oacc[dt][r] * ir[r]);
}

extern "C" void kernel_launch(void* const* d_in, const int* in_sizes, int n_in,
                              void* d_out, int out_size, void* d_ws, size_t ws_size,
                              hipStream_t stream) {
    const float* src = (const float*)d_in[0];
    const float* tgt = (const float*)d_in[1];
    const float* qw  = (const float*)d_in[2];
    const float* qb  = (const float*)d_in[3];
    const float* kw  = (const float*)d_in[4];
    const float* kb  = (const float*)d_in[5];
    const float* vw  = (const float*)d_in[6];
    const float* vb  = (const float*)d_in[7];
    const float* ow  = (const float*)d_in[8];
    const float* ob  = (const float*)d_in[9];
    float* out = (float*)d_out;

    const size_t TEN = (size_t)NBATCH * DIM * NPIX;  // 4,718,592
    bf16* Wbf  = (bf16*)d_ws;          // 4 x 65536
    bf16* XbfS = Wbf  + 4 * 65536;     // (b,n,c)
    bf16* XbfT = XbfS + TEN;           // (b,n,c)
    bf16* Qt   = XbfT + TEN;           // (b,h,n,d), prescaled
    bf16* Kt   = Qt   + TEN;           // (b,h,n,d)
    bf16* Vt   = Kt   + TEN;           // (b,c,n)
    bf16* Op   = Vt   + TEN;           // (b,n,c)

    cvt_w_kernel<<<dim3(32, 4, 1), 256, 0, stream>>>(qw, kw, vw, ow, Wbf);
    txp_kernel<<<dim3(NPIX / 64, DIM / 64, 2 * NBATCH), 256, 0, stream>>>(src, tgt, XbfS, XbfT);

    dim3 cgrid(NPIX / 64, 2, NBATCH);
    conv_kernel<1><<<cgrid, 256, 0, stream>>>(XbfS, Wbf,             qb, SCALE_L2E, Qt, nullptr);
    conv_kernel<1><<<cgrid, 256, 0, stream>>>(XbfT, Wbf + 1 * 65536, kb, 1.0f,      Kt, nullptr);
    conv_kernel<2><<<cgrid, 256, 0, stream>>>(XbfT, Wbf + 2 * 65536, vb, 1.0f,      Vt, nullptr);

    attn_kernel<<<dim3(NPIX / 64, NHEADS, NBATCH), 256, 0, stream>>>(Qt, Kt, Vt, Op);

    conv_kernel<0><<<cgrid, 256, 0, stream>>>(Op, Wbf + 3 * 65536, ob, 1.0f, nullptr, out);
}

// Round 7
// 272.236 us; speedup vs baseline: 11.1184x; 1.8701x over previous
//
#include <hip/hip_runtime.h>
#include <hip/hip_bf16.h>

#define DIM 256
#define NHEADS 4
#define HDIM 64
#define NPIX 2304          // 48*48
#define NBATCH 8
#define SCALE_L2E 0.18033688011112042f   // 0.125 * log2(e), folded into Q
#define CLAMP_L2E 8.656170245332781f     // 6.0  * log2(e)

typedef __hip_bfloat16 bf16;
typedef __bf16 bf16x8 __attribute__((ext_vector_type(8)));
typedef float  f32x4  __attribute__((ext_vector_type(4)));
typedef float  f32x16 __attribute__((ext_vector_type(16)));

__device__ __forceinline__ unsigned int pack2bf(float a, float b) {
    __hip_bfloat162 h = __float22bfloat162_rn(float2{a, b});
    union { __hip_bfloat162 h; unsigned int u; } c; c.h = h;
    return c.u;
}

// ---- 4 weight matrices (256x256 f32, row-major (m,c)) -> bf16, concatenated.
__global__ __launch_bounds__(256) void cvt_w_kernel(
    const float* __restrict__ w0, const float* __restrict__ w1,
    const float* __restrict__ w2, const float* __restrict__ w3,
    bf16* __restrict__ out)
{
    const int sel = blockIdx.y;
    const float* src = sel == 0 ? w0 : sel == 1 ? w1 : sel == 2 ? w2 : w3;
    const int i = (blockIdx.x * 256 + threadIdx.x) * 8;
    float4 a = *(const float4*)(src + i);
    float4 b = *(const float4*)(src + i + 4);
    uint4 u;
    u.x = pack2bf(a.x, a.y); u.y = pack2bf(a.z, a.w);
    u.z = pack2bf(b.x, b.y); u.w = pack2bf(b.z, b.w);
    *(uint4*)(void*)(out + (size_t)sel * 65536 + i) = u;
}

// ---- src/tgt (b,c,n) f32 -> (b,n,c) bf16 via LDS tile transpose.
__global__ __launch_bounds__(256) void txp_kernel(
    const float* __restrict__ src, const float* __restrict__ tgt,
    bf16* __restrict__ oS, bf16* __restrict__ oT)
{
    const int b = blockIdx.z & 7;
    const float* in = (blockIdx.z >> 3) ? tgt : src;
    bf16* out = (blockIdx.z >> 3) ? oT : oS;
    const int n0 = blockIdx.x * 64, c0 = blockIdx.y * 64;
    __shared__ float tile[64][65];
    const int t = threadIdx.x;
#pragma unroll
    for (int i = 0; i < 4; ++i) {
        int idx = t + i * 256;
        int cl = idx >> 4, n4 = (idx & 15) * 4;
        float4 v = *(const float4*)(in + ((size_t)b * DIM + c0 + cl) * NPIX + n0 + n4);
        tile[cl][n4] = v.x; tile[cl][n4 + 1] = v.y;
        tile[cl][n4 + 2] = v.z; tile[cl][n4 + 3] = v.w;
    }
    __syncthreads();
#pragma unroll
    for (int i = 0; i < 2; ++i) {
        int idx = t + i * 256;
        int nl = idx >> 3, c8 = (idx & 7) * 8;
        uint4 u;
        u.x = pack2bf(tile[c8 + 0][nl], tile[c8 + 1][nl]);
        u.y = pack2bf(tile[c8 + 2][nl], tile[c8 + 3][nl]);
        u.z = pack2bf(tile[c8 + 4][nl], tile[c8 + 5][nl]);
        u.w = pack2bf(tile[c8 + 6][nl], tile[c8 + 7][nl]);
        *(uint4*)(void*)(out + ((size_t)b * NPIX + n0 + nl) * DIM + c0 + c8) = u;
    }
}

// ---- 1x1 conv as MFMA GEMM: D[n][m] = sum_c X[n][c] * W[m][c] + bias[m].
// X: (b,n,c) bf16; W: (m,c) bf16. Block: 64 n x 128 m, 4 waves (16 n each).
// MODE 0: f32 natural (b,c,n) -> Yf (final out). MODE 1: bf16 (b,h,n,d)*scale -> Yb (Q,K).
// MODE 2: bf16 (b,c,n) -> Yb (V).
template <int MODE>
__global__ __launch_bounds__(256) void conv_kernel(
    const bf16* __restrict__ X, const bf16* __restrict__ Wb,
    const float* __restrict__ bias, float scale,
    bf16* __restrict__ Yb, float* __restrict__ Yf)
{
    const int b  = blockIdx.z, mh = blockIdx.y;
    const int n0 = blockIdx.x * 64;
    const int w  = threadIdx.x >> 6, l = threadIdx.x & 63;
    const int lo = l & 15, hi = l >> 4;
    const int nrow = n0 + w * 16 + lo;

    const bf16* xp = X + ((size_t)b * NPIX + nrow) * DIM + hi * 8;
    const bf16* wp = Wb + ((size_t)(mh * 128 + lo)) * DIM + hi * 8;

    f32x4 acc[8];
#pragma unroll
    for (int mt = 0; mt < 8; ++mt) acc[mt] = (f32x4){0.f, 0.f, 0.f, 0.f};

#pragma unroll 2
    for (int k0 = 0; k0 < DIM; k0 += 32) {
        bf16x8 a = *(const bf16x8*)(const void*)(xp + k0);
#pragma unroll
        for (int mt = 0; mt < 8; ++mt) {
            bf16x8 bf = *(const bf16x8*)(const void*)(wp + (size_t)mt * 16 * DIM + k0);
            acc[mt] = __builtin_amdgcn_mfma_f32_16x16x32_bf16(a, bf, acc[mt], 0, 0, 0);
        }
    }

    const int nb = n0 + w * 16 + hi * 4;   // first of 4 consecutive n (rows r)
#pragma unroll
    for (int mt = 0; mt < 8; ++mt) {
        const int m = mh * 128 + mt * 16 + lo;
        const float bv = bias[m];
        if (MODE == 1) {
            const int h = m >> 6, d = m & 63;
            bf16* p = Yb + (((size_t)b * NHEADS + h) * NPIX + nb) * HDIM + d;
#pragma unroll
            for (int r = 0; r < 4; ++r)
                p[(size_t)r * HDIM] = __float2bfloat16((acc[mt][r] + bv) * scale);
        } else if (MODE == 2) {
            bf16* p = Yb + ((size_t)b * DIM + m) * NPIX + nb;
            *(unsigned int*)(void*)(p)     = pack2bf(acc[mt][0] + bv, acc[mt][1] + bv);
            *(unsigned int*)(void*)(p + 2) = pack2bf(acc[mt][2] + bv, acc[mt][3] + bv);
        } else {
            float4 v = make_float4(acc[mt][0] + bv, acc[mt][1] + bv,
                                   acc[mt][2] + bv, acc[mt][3] + bv);
            *(float4*)(void*)(Yf + ((size_t)b * DIM + m) * NPIX + nb) = v;
        }
    }
}

// ---- MFMA flash attention, 32x32x16, no LDS, permlane-only cross-lane.
// Q,K: (b,h,n,d) bf16 (Q prescaled by SCALE_L2E). V: (b,c,n) bf16. Op: (b,n,c) bf16.
// Block: 1 wave = 64 queries (2 sub-tiles of 32). Grid: (36, 4, 8).
// QK^T swapped: S^T = mfma(K, Q) => lane(ln,h2) reg r holds
// S[key = k0 + (r&3)+8*(r>>2)+4*h2][q = nq + qs*32 + ln].
// PV B-frag (P^T) built with 4 v_permlane32_swap_b32 per 32 keys.
__global__ __launch_bounds__(64) void attn_kernel(
    const bf16* __restrict__ Qt, const bf16* __restrict__ Kt,
    const bf16* __restrict__ Vt, bf16* __restrict__ Op)
{
    const int b = blockIdx.z, h = blockIdx.y;
    const int l = threadIdx.x & 63;
    const int ln = l & 31, h2 = l >> 5;
    const int nq = blockIdx.x * 64;

    const size_t qkb = ((size_t)b * NHEADS + h) * (size_t)NPIX * HDIM;
    const bf16* Qb = Qt + qkb;
    const bf16* Kb = Kt + qkb;
    const bf16* Vb = Vt + ((size_t)b * DIM + h * HDIM) * (size_t)NPIX;

    // Q B-frags (held in regs): B[d_loc=h2*8+j][q=ln] for d-chunk dk
    bf16x8 qf[2][4];
#pragma unroll
    for (int qs = 0; qs < 2; ++qs)
#pragma unroll
        for (int dk = 0; dk < 4; ++dk)
            qf[qs][dk] = *(const bf16x8*)(const void*)(
                Qb + (size_t)(nq + qs * 32 + ln) * HDIM + dk * 16 + h2 * 8);

    f32x16 oacc[2][2];   // [qs][dt]: O^T[d = dt*32 + row][q]
#pragma unroll
    for (int qs = 0; qs < 2; ++qs)
#pragma unroll
        for (int dt = 0; dt < 2; ++dt)
#pragma unroll
            for (int r = 0; r < 16; ++r) oacc[qs][dt][r] = 0.f;
    float lsum[2] = {0.f, 0.f};

    for (int k0 = 0; k0 < NPIX; k0 += 32) {
        // K A-frags: A[key=ln][d_loc=h2*8+j], d-chunk dk
        bf16x8 kf[4];
#pragma unroll
        for (int dk = 0; dk < 4; ++dk)
            kf[dk] = *(const bf16x8*)(const void*)(
                Kb + (size_t)(k0 + ln) * HDIM + dk * 16 + h2 * 8);
        // V A-frags: A[d=dt*32+ln][k_loc=h2*8+j] for key-halves kb (16 keys each)
        bf16x8 vf[2][2];
#pragma unroll
        for (int kb = 0; kb < 2; ++kb)
#pragma unroll
            for (int dt = 0; dt < 2; ++dt)
                vf[kb][dt] = *(const bf16x8*)(const void*)(
                    Vb + (size_t)(dt * 32 + ln) * NPIX + k0 + kb * 16 + h2 * 8);

#pragma unroll
        for (int qs = 0; qs < 2; ++qs) {
            f32x16 s;
#pragma unroll
            for (int r = 0; r < 16; ++r) s[r] = 0.f;
#pragma unroll
            for (int dk = 0; dk < 4; ++dk)
                s = __builtin_amdgcn_mfma_f32_32x32x16_bf16(kf[dk], qf[qs][dk], s, 0, 0, 0);

            // P = exp2(clamp(S)); pack pairs: word p covers keys 8*(p>>1)+4*h2+2*(p&1)+{0,1}
            float ls = 0.f;
            unsigned int pk[8];
#pragma unroll
            for (int p = 0; p < 8; ++p) {
                float ea = exp2f(__builtin_amdgcn_fmed3f(s[2 * p],     -CLAMP_L2E, CLAMP_L2E));
                float eb = exp2f(__builtin_amdgcn_fmed3f(s[2 * p + 1], -CLAMP_L2E, CLAMP_L2E));
                ls += ea + eb;
                pk[p] = pack2bf(ea, eb);
            }
            lsum[qs] += ls;

            // Build P^T B-frags via half-wave swaps:
            // after swap(a,b): a = {a.lo32 | b.lo32}, b = {a.hi32 | b.hi32}
            unsigned int c00 = pk[0], c02 = pk[2], c01 = pk[1], c03 = pk[3];
            unsigned int c10 = pk[4], c12 = pk[6], c11 = pk[5], c13 = pk[7];
            asm("v_permlane32_swap_b32 %0, %1" : "+v"(c00), "+v"(c02));
            asm("v_permlane32_swap_b32 %0, %1" : "+v"(c01), "+v"(c03));
            asm("v_permlane32_swap_b32 %0, %1" : "+v"(c10), "+v"(c12));
            asm("v_permlane32_swap_b32 %0, %1" : "+v"(c11), "+v"(c13));
            union { unsigned int u[4]; bf16x8 v; } pb0, pb1;
            pb0.u[0] = c00; pb0.u[1] = c01; pb0.u[2] = c02; pb0.u[3] = c03;
            pb1.u[0] = c10; pb1.u[1] = c11; pb1.u[2] = c12; pb1.u[3] = c13;

#pragma unroll
            for (int dt = 0; dt < 2; ++dt) {
                oacc[qs][dt] = __builtin_amdgcn_mfma_f32_32x32x16_bf16(vf[0][dt], pb0.v, oacc[qs][dt], 0, 0, 0);
                oacc[qs][dt] = __builtin_amdgcn_mfma_f32_32x32x16_bf16(vf[1][dt], pb1.v, oacc[qs][dt], 0, 0, 0);
            }
        }
    }

    // normalize: lane's 32 outputs all belong to query q = nq + qs*32 + ln
    float inv[2];
#pragma unroll
    for (int qs = 0; qs < 2; ++qs) {
        float t = lsum[qs] + __shfl_xor(lsum[qs], 32);
        inv[qs] = 1.f / t;
    }

    // store Op (b,n,c): n = nq + qs*32 + ln; c = h*64 + dt*32 + 8*g + 4*h2 + (0..3)
#pragma unroll
    for (int qs = 0; qs < 2; ++qs) {
        bf16* rowp = Op + ((size_t)b * NPIX + nq + qs * 32 + ln) * DIM + h * HDIM;
#pragma unroll
        for (int dt = 0; dt < 2; ++dt)
#pragma unroll
            for (int g = 0; g < 4; ++g) {
                float v0 = oacc[qs][dt][g * 4 + 0] * inv[qs];
                float v1 = oacc[qs][dt][g * 4 + 1] * inv[qs];
                float v2 = oacc[qs][dt][g * 4 + 2] * inv[qs];
                float v3 = oacc[qs][dt][g * 4 + 3] * inv[qs];
                uint2 u = make_uint2(pack2bf(v0, v1), pack2bf(v2, v3));
                *(uint2*)(void*)(rowp + dt * 32 + g * 8 + h2 * 4) = u;
            }
    }
}

extern "C" void kernel_launch(void* const* d_in, const int* in_sizes, int n_in,
                              void* d_out, int out_size, void* d_ws, size_t ws_size,
                              hipStream_t stream) {
    const float* src = (const float*)d_in[0];
    const float* tgt = (const float*)d_in[1];
    const float* qw  = (const float*)d_in[2];
    const float* qb  = (const float*)d_in[3];
    const float* kw  = (const float*)d_in[4];
    const float* kb  = (const float*)d_in[5];
    const float* vw  = (const float*)d_in[6];
    const float* vb  = (const float*)d_in[7];
    const float* ow  = (const float*)d_in[8];
    const float* ob  = (const float*)d_in[9];
    float* out = (float*)d_out;

    const size_t TEN = (size_t)NBATCH * DIM * NPIX;  // 4,718,592
    bf16* Wbf  = (bf16*)d_ws;          // 4 x 65536
    bf16* XbfS = Wbf  + 4 * 65536;     // (b,n,c)
    bf16* XbfT = XbfS + TEN;           // (b,n,c)
    bf16* Qt   = XbfT + TEN;           // (b,h,n,d), prescaled
    bf16* Kt   = Qt   + TEN;           // (b,h,n,d)
    bf16* Vt   = Kt   + TEN;           // (b,c,n)
    bf16* Op   = Vt   + TEN;           // (b,n,c)

    cvt_w_kernel<<<dim3(32, 4, 1), 256, 0, stream>>>(qw, kw, vw, ow, Wbf);
    txp_kernel<<<dim3(NPIX / 64, DIM / 64, 2 * NBATCH), 256, 0, stream>>>(src, tgt, XbfS, XbfT);

    dim3 cgrid(NPIX / 64, 2, NBATCH);
    conv_kernel<1><<<cgrid, 256, 0, stream>>>(XbfS, Wbf,             qb, SCALE_L2E, Qt, nullptr);
    conv_kernel<1><<<cgrid, 256, 0, stream>>>(XbfT, Wbf + 1 * 65536, kb, 1.0f,      Kt, nullptr);
    conv_kernel<2><<<cgrid, 256, 0, stream>>>(XbfT, Wbf + 2 * 65536, vb, 1.0f,      Vt, nullptr);

    attn_kernel<<<dim3(NPIX / 64, NHEADS, NBATCH), 64, 0, stream>>>(Qt, Kt, Vt, Op);

    conv_kernel<0><<<cgrid, 256, 0, stream>>>(Op, Wbf + 3 * 65536, ob, 1.0f, nullptr, out);
}